// Round 1
// baseline (347.374 us; speedup 1.0000x reference)
//
#include <hip/hip_runtime.h>
#include <cmath>

#define WS 11
#define TILE 32
#define IN_TILE (TILE + WS - 1)   // 42
#define IMH 512
#define IMW 512
#define OH 502
#define OW 502
#define NPLANES 96                 // 32 * 3
#define NOUT ((long long)NPLANES * OH * OW)  // 24192384

struct GaussW { float g[WS]; };

// ---------------- kernel 1: range-detection flags over img1 ----------------
__global__ __launch_bounds__(256) void flags_kernel(const float* __restrict__ img1,
                                                    unsigned* __restrict__ flags,
                                                    int n4) {
    int idx = blockIdx.x * blockDim.x + threadIdx.x;
    int stride = gridDim.x * blockDim.x;
    int gt = 0, lt = 0;
    const float4* p = reinterpret_cast<const float4*>(img1);
    for (int i = idx; i < n4; i += stride) {
        float4 v = p[i];
        gt |= (v.x > 128.f) | (v.y > 128.f) | (v.z > 128.f) | (v.w > 128.f);
        lt |= (v.x < -0.5f) | (v.y < -0.5f) | (v.z < -0.5f) | (v.w < -0.5f);
    }
    if (gt) atomicOr(&flags[0], 1u);
    if (lt) atomicOr(&flags[1], 1u);
}

// ---------------- kernel 2: tiled separable SSIM + reduction ----------------
__global__ __launch_bounds__(256) void ssim_kernel(const float* __restrict__ img1,
                                                   const float* __restrict__ img2,
                                                   const unsigned* __restrict__ flags,
                                                   double* __restrict__ sum_out,
                                                   GaussW gw) {
    __shared__ float s1[IN_TILE][IN_TILE + 1];   // 42 x 43
    __shared__ float s2[IN_TILE][IN_TILE + 1];
    __shared__ float vv[5][TILE][IN_TILE + 1];   // 5 x 32 x 43

    const int plane = blockIdx.z;
    const int tx0 = blockIdx.x * TILE;   // output col origin
    const int ty0 = blockIdx.y * TILE;   // output row origin
    const float* p1 = img1 + (size_t)plane * IMH * IMW;
    const float* p2 = img2 + (size_t)plane * IMH * IMW;
    const int tid = threadIdx.x;

    // ---- load halo tiles ----
    for (int i = tid; i < IN_TILE * IN_TILE; i += 256) {
        int r = i / IN_TILE, c = i - r * IN_TILE;
        int gr = ty0 + r, gc = tx0 + c;
        float a = 0.f, b = 0.f;
        if (gr < IMH && gc < IMW) {
            a = p1[gr * IMW + gc];
            b = p2[gr * IMW + gc];
        }
        s1[r][c] = a;
        s2[r][c] = b;
    }
    __syncthreads();

    // ---- vertical Gaussian pass: 5 quantities ----
    for (int i = tid; i < TILE * IN_TILE; i += 256) {
        int r = i / IN_TILE, c = i - r * IN_TILE;
        float m1 = 0.f, m2 = 0.f, q1 = 0.f, q2 = 0.f, q12 = 0.f;
        #pragma unroll
        for (int k = 0; k < WS; ++k) {
            float g = gw.g[k];
            float a = s1[r + k][c];
            float b = s2[r + k][c];
            m1  += g * a;
            m2  += g * b;
            q1  += g * (a * a);
            q2  += g * (b * b);
            q12 += g * (a * b);
        }
        vv[0][r][c] = m1;
        vv[1][r][c] = m2;
        vv[2][r][c] = q1;
        vv[3][r][c] = q2;
        vv[4][r][c] = q12;
    }
    __syncthreads();

    // ---- constants from range flags ----
    float maxv = flags[0] ? 255.f : 1.f;
    float minv = flags[1] ? -1.f : 0.f;
    float L = maxv - minv;
    float C1 = (0.01f * L) * (0.01f * L);
    float C2 = (0.03f * L) * (0.03f * L);

    // ---- horizontal Gaussian pass + SSIM map + local accumulate ----
    float local = 0.f;
    for (int i = tid; i < TILE * TILE; i += 256) {
        int r = i >> 5, c = i & 31;
        int oy = ty0 + r, ox = tx0 + c;
        if (oy < OH && ox < OW) {
            float mu1 = 0.f, mu2 = 0.f, x2 = 0.f, y2 = 0.f, xy = 0.f;
            #pragma unroll
            for (int k = 0; k < WS; ++k) {
                float g = gw.g[k];
                mu1 += g * vv[0][r][c + k];
                mu2 += g * vv[1][r][c + k];
                x2  += g * vv[2][r][c + k];
                y2  += g * vv[3][r][c + k];
                xy  += g * vv[4][r][c + k];
            }
            float mu1s = mu1 * mu1, mu2s = mu2 * mu2, mu12 = mu1 * mu2;
            float sg1 = x2 - mu1s, sg2 = y2 - mu2s, sg12 = xy - mu12;
            float v1 = 2.f * sg12 + C2;
            float v2 = sg1 + sg2 + C2;
            float num = (2.f * mu12 + C1) * v1;
            float den = (mu1s + mu2s + C1) * v2;
            local += num / den;
        }
    }

    // ---- block reduction: wave shfl tree, then cross-wave, then double atomic ----
    #pragma unroll
    for (int off = 32; off > 0; off >>= 1)
        local += __shfl_down(local, off, 64);

    __shared__ float wsum[4];
    int wave = tid >> 6, lane = tid & 63;
    if (lane == 0) wsum[wave] = local;
    __syncthreads();
    if (tid == 0) {
        double t = (double)wsum[0] + (double)wsum[1] + (double)wsum[2] + (double)wsum[3];
        atomicAdd(sum_out, t);
    }
}

// ---------------- kernel 3: finalize mean ----------------
__global__ void finalize_kernel(const double* __restrict__ sum, float* __restrict__ out) {
    out[0] = (float)(sum[0] / (double)NOUT);
}

extern "C" void kernel_launch(void* const* d_in, const int* in_sizes, int n_in,
                              void* d_out, int out_size, void* d_ws, size_t ws_size,
                              hipStream_t stream) {
    const float* img1 = (const float*)d_in[0];
    const float* img2 = (const float*)d_in[1];
    float* out = (float*)d_out;

    // workspace layout: [0..3] flag_gt128, [4..7] flag_lt-0.5, [8..15] double sum
    unsigned* flags = (unsigned*)d_ws;
    double* sum = (double*)((char*)d_ws + 8);

    // zero flags + accumulator (harness poisons d_ws)
    hipMemsetAsync(d_ws, 0, 16, stream);

    // Gaussian taps (float64 math then cast, matching numpy reference)
    GaussW gw;
    {
        double g[WS], s = 0.0;
        for (int i = 0; i < WS; ++i) {
            double x = (double)(i - WS / 2);
            g[i] = exp(-(x * x) / (2.0 * 1.5 * 1.5));
            s += g[i];
        }
        for (int i = 0; i < WS; ++i) gw.g[i] = (float)(g[i] / s);
    }

    int n = in_sizes[0];           // 25,165,824 floats
    int n4 = n / 4;
    flags_kernel<<<2048, 256, 0, stream>>>(img1, flags, n4);

    dim3 grid((OW + TILE - 1) / TILE, (OH + TILE - 1) / TILE, NPLANES); // 16x16x96
    ssim_kernel<<<grid, 256, 0, stream>>>(img1, img2, flags, sum, gw);

    finalize_kernel<<<1, 1, 0, stream>>>(sum, out);
}

// Round 2
// 346.056 us; speedup vs baseline: 1.0038x; 1.0038x over previous
//
#include <hip/hip_runtime.h>
#include <cmath>

#define WS 11
#define TILE 32
#define IN_TILE (TILE + WS - 1)   // 42
#define PADW 44                    // padded row length (floats): 16B-aligned, bank skew 12
#define IMH 512
#define IMW 512
#define OH 502
#define OW 502
#define NPLANES 96                 // 32 * 3
#define NOUT ((long long)NPLANES * OH * OW)  // 24192384

struct GaussW { float g[WS]; };

// ---------------- kernel 1: range-detection flags over img1 ----------------
__global__ __launch_bounds__(256) void flags_kernel(const float* __restrict__ img1,
                                                    unsigned* __restrict__ flags,
                                                    int n4) {
    int idx = blockIdx.x * blockDim.x + threadIdx.x;
    int stride = gridDim.x * blockDim.x;
    int gt = 0, lt = 0;
    const float4* p = reinterpret_cast<const float4*>(img1);
    for (int i = idx; i < n4; i += stride) {
        float4 v = p[i];
        gt |= (v.x > 128.f) | (v.y > 128.f) | (v.z > 128.f) | (v.w > 128.f);
        lt |= (v.x < -0.5f) | (v.y < -0.5f) | (v.z < -0.5f) | (v.w < -0.5f);
    }
    if (gt) atomicOr(&flags[0], 1u);
    if (lt) atomicOr(&flags[1], 1u);
}

// ---------------- kernel 2: tiled separable SSIM + reduction ----------------
__global__ __launch_bounds__(256) void ssim_kernel(const float* __restrict__ img1,
                                                   const float* __restrict__ img2,
                                                   const unsigned* __restrict__ flags,
                                                   double* __restrict__ sum_out,
                                                   GaussW gw) {
    __shared__ float s1[IN_TILE][PADW];     // 42 x 44
    __shared__ float s2[IN_TILE][PADW];
    __shared__ float vv[5][TILE][PADW];     // 5 x 32 x 44

    const int plane = blockIdx.z;
    const int tx0 = blockIdx.x * TILE;   // output col origin
    const int ty0 = blockIdx.y * TILE;   // output row origin
    const float* p1 = img1 + (size_t)plane * IMH * IMW;
    const float* p2 = img2 + (size_t)plane * IMH * IMW;
    const int tid = threadIdx.x;

    // ---- stage halo tiles (float4 groups: 42 rows x 11 groups) ----
    for (int i = tid; i < IN_TILE * 11; i += 256) {
        int r = i / 11, cg = i - r * 11;
        int gr = ty0 + r, gc = tx0 + cg * 4;
        float4 a = make_float4(0.f, 0.f, 0.f, 0.f);
        float4 b = make_float4(0.f, 0.f, 0.f, 0.f);
        if (gr < IMH) {
            const float* r1 = p1 + (size_t)gr * IMW;
            const float* r2 = p2 + (size_t)gr * IMW;
            if (gc + 3 < IMW) {
                a = *reinterpret_cast<const float4*>(r1 + gc);
                b = *reinterpret_cast<const float4*>(r2 + gc);
            } else {
                float ta[4] = {0.f, 0.f, 0.f, 0.f};
                float tb[4] = {0.f, 0.f, 0.f, 0.f};
                #pragma unroll
                for (int j = 0; j < 4; ++j) {
                    int c = gc + j;
                    if (c < IMW) { ta[j] = r1[c]; tb[j] = r2[c]; }
                }
                a = make_float4(ta[0], ta[1], ta[2], ta[3]);
                b = make_float4(tb[0], tb[1], tb[2], tb[3]);
            }
        }
        *reinterpret_cast<float4*>(&s1[r][cg * 4]) = a;
        *reinterpret_cast<float4*>(&s2[r][cg * 4]) = b;
    }
    __syncthreads();

    // ---- vertical Gaussian pass: 5 quantities, float4 per item ----
    for (int i = tid; i < TILE * 11; i += 256) {
        int r = i / 11, cg = i - r * 11;
        float m1[4] = {0,0,0,0}, m2[4] = {0,0,0,0};
        float q1[4] = {0,0,0,0}, q2[4] = {0,0,0,0}, q12[4] = {0,0,0,0};
        #pragma unroll
        for (int k = 0; k < WS; ++k) {
            float w = gw.g[k];
            float4 a4 = *reinterpret_cast<const float4*>(&s1[r + k][cg * 4]);
            float4 b4 = *reinterpret_cast<const float4*>(&s2[r + k][cg * 4]);
            float a[4] = {a4.x, a4.y, a4.z, a4.w};
            float b[4] = {b4.x, b4.y, b4.z, b4.w};
            #pragma unroll
            for (int j = 0; j < 4; ++j) {
                m1[j]  += w * a[j];
                m2[j]  += w * b[j];
                q1[j]  += w * (a[j] * a[j]);
                q2[j]  += w * (b[j] * b[j]);
                q12[j] += w * (a[j] * b[j]);
            }
        }
        *reinterpret_cast<float4*>(&vv[0][r][cg * 4]) = make_float4(m1[0], m1[1], m1[2], m1[3]);
        *reinterpret_cast<float4*>(&vv[1][r][cg * 4]) = make_float4(m2[0], m2[1], m2[2], m2[3]);
        *reinterpret_cast<float4*>(&vv[2][r][cg * 4]) = make_float4(q1[0], q1[1], q1[2], q1[3]);
        *reinterpret_cast<float4*>(&vv[3][r][cg * 4]) = make_float4(q2[0], q2[1], q2[2], q2[3]);
        *reinterpret_cast<float4*>(&vv[4][r][cg * 4]) = make_float4(q12[0], q12[1], q12[2], q12[3]);
    }
    __syncthreads();

    // ---- constants from range flags ----
    float maxv = flags[0] ? 255.f : 1.f;
    float minv = flags[1] ? -1.f : 0.f;
    float L = maxv - minv;
    float C1 = (0.01f * L) * (0.01f * L);
    float C2 = (0.03f * L) * (0.03f * L);

    // ---- horizontal pass: exactly 256 items, 4 outputs each ----
    float local = 0.f;
    {
        const int r = tid >> 3;          // 0..31
        const int cg = tid & 7;          // 0..7 -> output cols cg*4 .. cg*4+3
        // load 16-float sliding windows per quantity (4 x b128 each)
        float w0[16], w1[16], w2[16], w3[16], w4[16];
        #pragma unroll
        for (int t = 0; t < 4; ++t) {
            float4 v0 = *reinterpret_cast<const float4*>(&vv[0][r][cg * 4 + t * 4]);
            float4 v1 = *reinterpret_cast<const float4*>(&vv[1][r][cg * 4 + t * 4]);
            float4 v2 = *reinterpret_cast<const float4*>(&vv[2][r][cg * 4 + t * 4]);
            float4 v3 = *reinterpret_cast<const float4*>(&vv[3][r][cg * 4 + t * 4]);
            float4 v4 = *reinterpret_cast<const float4*>(&vv[4][r][cg * 4 + t * 4]);
            w0[t*4+0]=v0.x; w0[t*4+1]=v0.y; w0[t*4+2]=v0.z; w0[t*4+3]=v0.w;
            w1[t*4+0]=v1.x; w1[t*4+1]=v1.y; w1[t*4+2]=v1.z; w1[t*4+3]=v1.w;
            w2[t*4+0]=v2.x; w2[t*4+1]=v2.y; w2[t*4+2]=v2.z; w2[t*4+3]=v2.w;
            w3[t*4+0]=v3.x; w3[t*4+1]=v3.y; w3[t*4+2]=v3.z; w3[t*4+3]=v3.w;
            w4[t*4+0]=v4.x; w4[t*4+1]=v4.y; w4[t*4+2]=v4.z; w4[t*4+3]=v4.w;
        }
        const int oy = ty0 + r;
        #pragma unroll
        for (int j = 0; j < 4; ++j) {
            float mu1 = 0.f, mu2 = 0.f, x2 = 0.f, y2 = 0.f, xy = 0.f;
            #pragma unroll
            for (int k = 0; k < WS; ++k) {
                float w = gw.g[k];
                mu1 += w * w0[j + k];
                mu2 += w * w1[j + k];
                x2  += w * w2[j + k];
                y2  += w * w3[j + k];
                xy  += w * w4[j + k];
            }
            int ox = tx0 + cg * 4 + j;
            if (oy < OH && ox < OW) {
                float mu1s = mu1 * mu1, mu2s = mu2 * mu2, mu12 = mu1 * mu2;
                float sg1 = x2 - mu1s, sg2 = y2 - mu2s, sg12 = xy - mu12;
                float v1 = 2.f * sg12 + C2;
                float v2 = sg1 + sg2 + C2;
                float num = (2.f * mu12 + C1) * v1;
                float den = (mu1s + mu2s + C1) * v2;
                float rc = __builtin_amdgcn_rcpf(den);
                rc = rc * (2.0f - den * rc);   // 1 Newton step
                local += num * rc;
            }
        }
    }

    // ---- block reduction: wave shfl tree, then cross-wave, then double atomic ----
    #pragma unroll
    for (int off = 32; off > 0; off >>= 1)
        local += __shfl_down(local, off, 64);

    __shared__ float wsum[4];
    int wave = tid >> 6, lane = tid & 63;
    if (lane == 0) wsum[wave] = local;
    __syncthreads();
    if (tid == 0) {
        double t = (double)wsum[0] + (double)wsum[1] + (double)wsum[2] + (double)wsum[3];
        atomicAdd(sum_out, t);
    }
}

// ---------------- kernel 3: finalize mean ----------------
__global__ void finalize_kernel(const double* __restrict__ sum, float* __restrict__ out) {
    out[0] = (float)(sum[0] / (double)NOUT);
}

extern "C" void kernel_launch(void* const* d_in, const int* in_sizes, int n_in,
                              void* d_out, int out_size, void* d_ws, size_t ws_size,
                              hipStream_t stream) {
    const float* img1 = (const float*)d_in[0];
    const float* img2 = (const float*)d_in[1];
    float* out = (float*)d_out;

    // workspace layout: [0..3] flag_gt128, [4..7] flag_lt-0.5, [8..15] double sum
    unsigned* flags = (unsigned*)d_ws;
    double* sum = (double*)((char*)d_ws + 8);

    hipMemsetAsync(d_ws, 0, 16, stream);

    // Gaussian taps (float64 math then cast, matching numpy reference)
    GaussW gw;
    {
        double g[WS], s = 0.0;
        for (int i = 0; i < WS; ++i) {
            double x = (double)(i - WS / 2);
            g[i] = exp(-(x * x) / (2.0 * 1.5 * 1.5));
            s += g[i];
        }
        for (int i = 0; i < WS; ++i) gw.g[i] = (float)(g[i] / s);
    }

    int n = in_sizes[0];           // 25,165,824 floats
    int n4 = n / 4;
    flags_kernel<<<2048, 256, 0, stream>>>(img1, flags, n4);

    dim3 grid((OW + TILE - 1) / TILE, (OH + TILE - 1) / TILE, NPLANES); // 16x16x96
    ssim_kernel<<<grid, 256, 0, stream>>>(img1, img2, flags, sum, gw);

    finalize_kernel<<<1, 1, 0, stream>>>(sum, out);
}